// Round 2
// baseline (76.451 us; speedup 1.0000x reference)
//
#include <hip/hip_runtime.h>

// Problem constants (from reference setup_inputs)
#define BB 32     // batch
#define UU 1152   // input_units
#define NN 10     // num_units
#define CC 8      // input_channels
#define DD 16     // channels_per_unit
#define EPS 1e-8f

// inputs : (B, C, U)        float32
// weights: (U, N, C, D)     float32
// out    : (B, N, U, C, D)  float32
//
// pondered[b,u,n,c,d] = weights[u,n,c,d] * inputs[b,c,u]
// Routing is fully local to each 16-element (b,u,n,c,:) vector -> 1 thread/group.
//
// Register-lean formulation (target <=64 VGPR for 8 waves/SIMD):
//   iter0 folded:  logits = (scale0/16) * p^2           (softmax is uniform)
//   iters 1,2:     e_i = exp(logits_i)   (no max-sub: |logits| <= ~40, safe in fp32)
//                  t_i = e_i * p_i ;  sum = SUM e_i ; sqt = SUM t_i^2
//                  inv = 1/sum ; sq = sqt*inv^2 ; k = sq/(1+sq)*rsqrt(sq+eps)*inv
//                  o_i = k * t_i  (never materialized except last iter's store)
//                  logits_i += p_i * o_i   (skipped on last iter - dead)
// Live arrays: p[16], logits[16], e[16]  = 48 VGPRs + temps.

__device__ __forceinline__ float rcp_fast(float x) { return __builtin_amdgcn_rcpf(x); }
__device__ __forceinline__ float rsq_fast(float x) { return __builtin_amdgcn_rsqf(x); }

// 4-way-accumulator tree sum of a[0..15] (dep chain ~6 instead of 15)
#define TREE_SUM4(a, dst)                                              \
    do {                                                               \
        float _s0 = a[0] + a[4], _s1 = a[1] + a[5];                    \
        float _s2 = a[2] + a[6], _s3 = a[3] + a[7];                    \
        _s0 += a[8];  _s1 += a[9];  _s2 += a[10]; _s3 += a[11];        \
        _s0 += a[12]; _s1 += a[13]; _s2 += a[14]; _s3 += a[15];        \
        dst = (_s0 + _s1) + (_s2 + _s3);                               \
    } while (0)

__global__ __launch_bounds__(256, 8) void caps_route_kernel(
    const float* __restrict__ inputs,
    const float* __restrict__ weights,
    float* __restrict__ out)
{
    int t = blockIdx.x * blockDim.x + threadIdx.x;  // total 2,949,120 < 2^31

    // decode: c fastest (8), then u (1152), then n (10), then b
    int c  = t & 7;
    int t2 = t >> 3;
    int u  = t2 % UU;
    int t3 = t2 / UU;
    int n  = t3 % NN;
    int b  = t3 / NN;

    float v = inputs[(b * CC + c) * UU + u];
    const float* wp = weights + ((u * NN + n) * CC + c) * DD;

    float p[DD];
    #pragma unroll
    for (int i = 0; i < DD; i += 4) {
        float4 w4 = *reinterpret_cast<const float4*>(wp + i);
        p[i]   = w4.x * v;
        p[i+1] = w4.y * v;
        p[i+2] = w4.z * v;
        p[i+3] = w4.w * v;
    }

    // ---- iteration 0 (folded): logits = (scale0/16) * p^2 ----
    float logits[DD];
    {
        float e[DD];
        #pragma unroll
        for (int i = 0; i < DD; ++i) e[i] = p[i] * p[i];
        float sqr;
        TREE_SUM4(e, sqr);
        float sq = sqr * (1.0f / 256.0f);           // ||s||^2, s = p/16
        float scale = sq * rcp_fast(1.0f + sq) * rsq_fast(sq + EPS);
        float kk = scale * (1.0f / 16.0f);
        #pragma unroll
        for (int i = 0; i < DD; ++i) logits[i] = kk * e[i];
    }

    // ---- iteration 1 (with logits update) ----
    {
        float e[DD];
        #pragma unroll
        for (int i = 0; i < DD; ++i) e[i] = __expf(logits[i]);
        float sum;
        TREE_SUM4(e, sum);
        #pragma unroll
        for (int i = 0; i < DD; ++i) e[i] *= p[i];  // t_i = e_i * p_i
        float sqt;
        {
            float q[DD];
            #pragma unroll
            for (int i = 0; i < DD; ++i) q[i] = e[i] * e[i];
            TREE_SUM4(q, sqt);
        }
        float inv = rcp_fast(sum);
        float sq = sqt * inv * inv;
        float k = sq * rcp_fast(1.0f + sq) * rsq_fast(sq + EPS) * inv;
        #pragma unroll
        for (int i = 0; i < DD; ++i)
            logits[i] = fmaf(k * p[i], e[i], logits[i]);  // += p_i * o_i
    }

    // ---- iteration 2 (final; logits update is dead) ----
    float* op = out + (((b * NN + n) * UU + u) * CC + c) * DD;
    {
        float e[DD];
        #pragma unroll
        for (int i = 0; i < DD; ++i) e[i] = __expf(logits[i]);
        float sum;
        TREE_SUM4(e, sum);
        #pragma unroll
        for (int i = 0; i < DD; ++i) e[i] *= p[i];  // t_i
        float sqt;
        {
            float q[DD];
            #pragma unroll
            for (int i = 0; i < DD; ++i) q[i] = e[i] * e[i];
            TREE_SUM4(q, sqt);
        }
        float inv = rcp_fast(sum);
        float sq = sqt * inv * inv;
        float k = sq * rcp_fast(1.0f + sq) * rsq_fast(sq + EPS) * inv;
        #pragma unroll
        for (int i = 0; i < DD; i += 4) {
            float4 r;
            r.x = k * e[i];
            r.y = k * e[i+1];
            r.z = k * e[i+2];
            r.w = k * e[i+3];
            *reinterpret_cast<float4*>(op + i) = r;
        }
    }
}

extern "C" void kernel_launch(void* const* d_in, const int* in_sizes, int n_in,
                              void* d_out, int out_size, void* d_ws, size_t ws_size,
                              hipStream_t stream) {
    const float* inputs  = (const float*)d_in[0];
    const float* weights = (const float*)d_in[1];
    float* out = (float*)d_out;

    const long long total = (long long)BB * NN * UU * CC;  // 2,949,120 = 11520*256
    const int block = 256;
    const int grid = (int)(total / block);                 // exact
    caps_route_kernel<<<grid, block, 0, stream>>>(inputs, weights, out);
}

// Round 3
// 50.273 us; speedup vs baseline: 1.5207x; 1.5207x over previous
//
#include <hip/hip_runtime.h>

// Problem constants (from reference setup_inputs)
#define BB 32     // batch
#define UU 1152   // input_units
#define NN 10     // num_units
#define CC 8      // input_channels
#define DD 16     // channels_per_unit
#define EPS 1e-8f

// inputs : (B, C, U)        float32
// weights: (U, N, C, D)     float32
// out    : (B, N, U, C, D)  float32
//
// pondered[b,u,n,c,d] = weights[u,n,c,d] * inputs[b,c,u]
// Routing is local to each 16-element (b,u,n,c,:) vector.
//
// R3 parallelization: FOUR threads per group, 4 d-elements each.
// Per-thread live state: p[4], logits[4], e[4] (~12 floats) -> ~32 VGPR
// -> 8 waves/SIMD naturally, short dependency chains.
// 16-element reductions = in-lane tree of 4 + 2-step DPP quad_perm butterfly
// (pure VALU, no LDS). Each lane-quad touches 64 contiguous bytes of
// weights/out -> fully coalesced.

__device__ __forceinline__ float rcp_fast(float x) { return __builtin_amdgcn_rcpf(x); }
__device__ __forceinline__ float rsq_fast(float x) { return __builtin_amdgcn_rsqf(x); }

// sum across the 4 lanes of a quad (lanes l, l^1, l^2, l^3)
__device__ __forceinline__ float quad_sum(float x) {
    // xor-1: quad_perm [1,0,3,2] = 0xB1
    float y = __int_as_float(
        __builtin_amdgcn_update_dpp(0, __float_as_int(x), 0xB1, 0xF, 0xF, true));
    x += y;
    // xor-2: quad_perm [2,3,0,1] = 0x4E
    y = __int_as_float(
        __builtin_amdgcn_update_dpp(0, __float_as_int(x), 0x4E, 0xF, 0xF, true));
    return x + y;
}

__global__ __launch_bounds__(256) void caps_route_kernel(
    const float* __restrict__ inputs,
    const float* __restrict__ weights,
    float* __restrict__ out)
{
    int t = blockIdx.x * blockDim.x + threadIdx.x;   // 11,796,480 threads
    int sub = t & 3;          // which 4-element slice of D
    int g   = t >> 2;         // group id: (b, n, u, c)

    int c  = g & 7;
    int g2 = g >> 3;
    int u  = g2 % UU;
    int g3 = g2 / UU;
    int n  = g3 % NN;
    int b  = g3 / NN;

    float v = inputs[(b * CC + c) * UU + u];

    const float* wp = weights + (((u * NN + n) * CC + c) * DD) + sub * 4;
    float4 w4 = *reinterpret_cast<const float4*>(wp);

    float p[4];
    p[0] = w4.x * v; p[1] = w4.y * v; p[2] = w4.z * v; p[3] = w4.w * v;

    // ---- iteration 0 (folded): softmax uniform -> logits = (scale0/16)*p^2 ----
    float logits[4];
    {
        float q0 = p[0] * p[0], q1 = p[1] * p[1];
        float q2 = p[2] * p[2], q3 = p[3] * p[3];
        float sqr = quad_sum((q0 + q1) + (q2 + q3));
        float sq = sqr * (1.0f / 256.0f);            // ||p/16||^2
        float scale = sq * rcp_fast(1.0f + sq) * rsq_fast(sq + EPS);
        float kk = scale * (1.0f / 16.0f);
        logits[0] = kk * q0; logits[1] = kk * q1;
        logits[2] = kk * q2; logits[3] = kk * q3;
    }

    // ---- iteration 1 (with logits update) ----
    {
        float e0 = __expf(logits[0]), e1 = __expf(logits[1]);
        float e2 = __expf(logits[2]), e3 = __expf(logits[3]);
        float sum = quad_sum((e0 + e1) + (e2 + e3));
        float t0 = e0 * p[0], t1 = e1 * p[1], t2 = e2 * p[2], t3 = e3 * p[3];
        float sqt = quad_sum((t0 * t0 + t1 * t1) + (t2 * t2 + t3 * t3));
        float inv = rcp_fast(sum);
        float sq = sqt * inv * inv;
        float k = sq * rcp_fast(1.0f + sq) * rsq_fast(sq + EPS) * inv;
        logits[0] = fmaf(k * p[0], t0, logits[0]);
        logits[1] = fmaf(k * p[1], t1, logits[1]);
        logits[2] = fmaf(k * p[2], t2, logits[2]);
        logits[3] = fmaf(k * p[3], t3, logits[3]);
    }

    // ---- iteration 2 (final; logits update dead) ----
    {
        float e0 = __expf(logits[0]), e1 = __expf(logits[1]);
        float e2 = __expf(logits[2]), e3 = __expf(logits[3]);
        float sum = quad_sum((e0 + e1) + (e2 + e3));
        float t0 = e0 * p[0], t1 = e1 * p[1], t2 = e2 * p[2], t3 = e3 * p[3];
        float sqt = quad_sum((t0 * t0 + t1 * t1) + (t2 * t2 + t3 * t3));
        float inv = rcp_fast(sum);
        float sq = sqt * inv * inv;
        float k = sq * rcp_fast(1.0f + sq) * rsq_fast(sq + EPS) * inv;

        float* op = out + ((((b * NN + n) * UU + u) * CC + c) * DD) + sub * 4;
        float4 r;
        r.x = k * t0; r.y = k * t1; r.z = k * t2; r.w = k * t3;
        *reinterpret_cast<float4*>(op) = r;
    }
}

extern "C" void kernel_launch(void* const* d_in, const int* in_sizes, int n_in,
                              void* d_out, int out_size, void* d_ws, size_t ws_size,
                              hipStream_t stream) {
    const float* inputs  = (const float*)d_in[0];
    const float* weights = (const float*)d_in[1];
    float* out = (float*)d_out;

    const long long total = (long long)BB * NN * UU * CC * 4;  // 11,796,480 = 46080*256
    const int block = 256;
    const int grid = (int)(total / block);                     // exact
    caps_route_kernel<<<grid, block, 0, stream>>>(inputs, weights, out);
}

// Round 5
// 46.307 us; speedup vs baseline: 1.6510x; 1.0857x over previous
//
#include <hip/hip_runtime.h>

// Problem constants (from reference setup_inputs)
#define BB 32     // batch
#define UU 1152   // input_units
#define NN 10     // num_units
#define CC 8      // input_channels
#define DD 16     // channels_per_unit
#define EPS 1e-8f
#define INV_LN2 1.44269504088896341f

// inputs : (B, C, U)        float32
// weights: (U, N, C, D)     float32
// out    : (B, N, U, C, D)  float32
//
// R5 = R4 with the nontemporal-store type fixed (clang ext_vector_type,
// not HIP_vector_type struct).
// One thread handles (b,u,c,sub-quad) for ALL 10 n values:
//  - input scalar + index decode amortized 10x
//  - 10 independent routing problems per thread; unroll 2 -> two chains
//    interleaved, multiple stores in flight per thread
//  - logits kept in base-2 domain (1/ln2 folded into update constant k)
//  - nontemporal float4 stores (pure streaming output, 189 MB >> L2)

typedef float f32x4 __attribute__((ext_vector_type(4)));

__device__ __forceinline__ float rcp_fast(float x) { return __builtin_amdgcn_rcpf(x); }
__device__ __forceinline__ float rsq_fast(float x) { return __builtin_amdgcn_rsqf(x); }

#if __has_builtin(__builtin_amdgcn_exp2f)
__device__ __forceinline__ float exp2_fast(float x) { return __builtin_amdgcn_exp2f(x); }
#else
__device__ __forceinline__ float exp2_fast(float x) { return __expf(x * 0.6931471805599453f); }
#endif

// sum across the 4 lanes of a quad — pure-VALU DPP butterfly
__device__ __forceinline__ float quad_sum(float x) {
    float y = __int_as_float(
        __builtin_amdgcn_update_dpp(0, __float_as_int(x), 0xB1, 0xF, 0xF, true)); // [1,0,3,2]
    x += y;
    y = __int_as_float(
        __builtin_amdgcn_update_dpp(0, __float_as_int(x), 0x4E, 0xF, 0xF, true)); // [2,3,0,1]
    return x + y;
}

__global__ __launch_bounds__(256) void caps_route_kernel(
    const float* __restrict__ inputs,
    const float* __restrict__ weights,
    float* __restrict__ out)
{
    int t = blockIdx.x * blockDim.x + threadIdx.x;  // 1,179,648 threads
    int sub = t & 3;          // 4-element slice of D
    int g   = t >> 2;         // (b, u, c) group
    int c   = g & 7;
    int g2  = g >> 3;
    int u   = g2 % UU;
    int b   = g2 / UU;

    float v = inputs[(b * CC + c) * UU + u];

    const float* wbase = weights + (u * NN * CC + c) * DD + sub * 4;
    float*       obase = out + ((b * NN * UU + u) * CC + c) * DD + sub * 4;

    #pragma unroll 2
    for (int n = 0; n < NN; ++n) {
        f32x4 w4 = *reinterpret_cast<const f32x4*>(wbase + n * (CC * DD));
        float p0 = w4.x * v, p1 = w4.y * v, p2 = w4.z * v, p3 = w4.w * v;

        // ---- iter 0 (folded): softmax uniform -> L = (scale0/16/ln2) * p^2 ----
        float q0 = p0 * p0, q1 = p1 * p1, q2 = p2 * p2, q3 = p3 * p3;
        float sqr = quad_sum((q0 + q1) + (q2 + q3));
        float sq0 = sqr * (1.0f / 256.0f);          // ||p/16||^2
        float scale0 = sq0 * rcp_fast(1.0f + sq0) * rsq_fast(sq0 + EPS);
        float kk = scale0 * (INV_LN2 / 16.0f);
        float L0 = kk * q0, L1 = kk * q1, L2 = kk * q2, L3 = kk * q3;

        // ---- iter 1 (with base-2 logits update) ----
        {
            float e0 = exp2_fast(L0), e1 = exp2_fast(L1);
            float e2 = exp2_fast(L2), e3 = exp2_fast(L3);
            float sum = quad_sum((e0 + e1) + (e2 + e3));
            float t0 = e0 * p0, t1 = e1 * p1, t2 = e2 * p2, t3 = e3 * p3;
            float sqt = quad_sum((t0 * t0 + t1 * t1) + (t2 * t2 + t3 * t3));
            float inv = rcp_fast(sum);
            float sq = sqt * inv * inv;
            float k = sq * rcp_fast(1.0f + sq) * rsq_fast(sq + EPS) * inv * INV_LN2;
            L0 = fmaf(k * p0, t0, L0); L1 = fmaf(k * p1, t1, L1);
            L2 = fmaf(k * p2, t2, L2); L3 = fmaf(k * p3, t3, L3);
        }

        // ---- iter 2 (final; logits update dead) ----
        {
            float e0 = exp2_fast(L0), e1 = exp2_fast(L1);
            float e2 = exp2_fast(L2), e3 = exp2_fast(L3);
            float sum = quad_sum((e0 + e1) + (e2 + e3));
            float t0 = e0 * p0, t1 = e1 * p1, t2 = e2 * p2, t3 = e3 * p3;
            float sqt = quad_sum((t0 * t0 + t1 * t1) + (t2 * t2 + t3 * t3));
            float inv = rcp_fast(sum);
            float sq = sqt * inv * inv;
            float k = sq * rcp_fast(1.0f + sq) * rsq_fast(sq + EPS) * inv;
            f32x4 r;
            r.x = k * t0; r.y = k * t1; r.z = k * t2; r.w = k * t3;
            __builtin_nontemporal_store(
                r, reinterpret_cast<f32x4*>(obase + n * (UU * CC * DD)));
        }
    }
}

extern "C" void kernel_launch(void* const* d_in, const int* in_sizes, int n_in,
                              void* d_out, int out_size, void* d_ws, size_t ws_size,
                              hipStream_t stream) {
    const float* inputs  = (const float*)d_in[0];
    const float* weights = (const float*)d_in[1];
    float* out = (float*)d_out;

    const long long total = (long long)BB * UU * CC * 4;  // 1,179,648 = 4608*256
    const int block = 256;
    const int grid = (int)(total / block);                // exact
    caps_route_kernel<<<grid, block, 0, stream>>>(inputs, weights, out);
}

// Round 6
// 44.839 us; speedup vs baseline: 1.7050x; 1.0327x over previous
//
#include <hip/hip_runtime.h>

// Problem constants (from reference setup_inputs)
#define BB 32     // batch
#define UU 1152   // input_units
#define NN 10     // num_units
#define CC 8      // input_channels
#define DD 16     // channels_per_unit
#define EPS 1e-8f
#define INV_LN2 1.44269504088896341f

// inputs : (B, C, U)        float32
// weights: (U, N, C, D)     float32
// out    : (B, N, U, C, D)  float32
//
// R6 = R5 + register slimming to get under the 64-VGPR occupancy cliff
// (8 waves/SIMD) without spill:
//  - squash coefficient folded: for S = sum(e), A = sum(t^2), t = e*p:
//      o_i = k_o * t_i,  k_o = A * rsqrt(A + eps*S^2) * rcp(S^2 + A)
//    (exactly scale/S of the reference; 2 trans instead of 3, fewer temps)
//  - iter1 uses m_i = e_i*q_i: t_i^2 = m_i*e_i and logit update = fma(k, m_i, L_i)
//    -> t never materialized in iter1
//  - logits in base-2 domain (INV_LN2 folded into k), raw v_exp_f32
//  - unroll 2: two independent routing chains interleaved
//  - __launch_bounds__(256, 8) pins the allocator at <=64 VGPR

typedef float f32x4 __attribute__((ext_vector_type(4)));

__device__ __forceinline__ float rcp_fast(float x) { return __builtin_amdgcn_rcpf(x); }
__device__ __forceinline__ float rsq_fast(float x) { return __builtin_amdgcn_rsqf(x); }

#if __has_builtin(__builtin_amdgcn_exp2f)
__device__ __forceinline__ float exp2_fast(float x) { return __builtin_amdgcn_exp2f(x); }
#else
__device__ __forceinline__ float exp2_fast(float x) { return __expf(x * 0.6931471805599453f); }
#endif

// sum across the 4 lanes of a quad — pure-VALU DPP butterfly
__device__ __forceinline__ float quad_sum(float x) {
    float y = __int_as_float(
        __builtin_amdgcn_update_dpp(0, __float_as_int(x), 0xB1, 0xF, 0xF, true)); // [1,0,3,2]
    x += y;
    y = __int_as_float(
        __builtin_amdgcn_update_dpp(0, __float_as_int(x), 0x4E, 0xF, 0xF, true)); // [2,3,0,1]
    return x + y;
}

__global__ __launch_bounds__(256, 8) void caps_route_kernel(
    const float* __restrict__ inputs,
    const float* __restrict__ weights,
    float* __restrict__ out)
{
    int t = blockIdx.x * blockDim.x + threadIdx.x;  // 1,179,648 threads
    int sub = t & 3;          // 4-element slice of D
    int g   = t >> 2;         // (b, u, c) group
    int c   = g & 7;
    int g2  = g >> 3;
    int u   = g2 % UU;
    int b   = g2 / UU;

    float v = inputs[(b * CC + c) * UU + u];

    const float* wbase = weights + (u * NN * CC + c) * DD + sub * 4;
    float*       obase = out + ((b * NN * UU + u) * CC + c) * DD + sub * 4;

    #pragma unroll 2
    for (int n = 0; n < NN; ++n) {
        f32x4 w4 = *reinterpret_cast<const f32x4*>(wbase + n * (CC * DD));
        float p0 = w4.x * v, p1 = w4.y * v, p2 = w4.z * v, p3 = w4.w * v;
        float q0 = p0 * p0, q1 = p1 * p1, q2 = p2 * p2, q3 = p3 * p3;

        // ---- iter 0 (folded): softmax uniform; L = scale0*INV_LN2/16 * q ----
        float sq0 = quad_sum((q0 + q1) + (q2 + q3)) * (1.0f / 256.0f);
        float kk = sq0 * rcp_fast(1.0f + sq0) * rsq_fast(sq0 + EPS)
                   * (INV_LN2 / 16.0f);
        float L0 = kk * q0, L1 = kk * q1, L2 = kk * q2, L3 = kk * q3;

        // ---- iter 1 (base-2 logit update via m = e*q) ----
        {
            float e0 = exp2_fast(L0), e1 = exp2_fast(L1);
            float e2 = exp2_fast(L2), e3 = exp2_fast(L3);
            float S  = quad_sum((e0 + e1) + (e2 + e3));
            float m0 = e0 * q0, m1 = e1 * q1, m2 = e2 * q2, m3 = e3 * q3;
            float A  = quad_sum((m0 * e0 + m1 * e1) + (m2 * e2 + m3 * e3));
            float Ssq = S * S;
            float k = A * rsq_fast(fmaf(EPS, Ssq, A)) * rcp_fast(Ssq + A)
                      * INV_LN2;
            L0 = fmaf(k, m0, L0); L1 = fmaf(k, m1, L1);
            L2 = fmaf(k, m2, L2); L3 = fmaf(k, m3, L3);
        }

        // ---- iter 2 (final; logit update dead) ----
        {
            float e0 = exp2_fast(L0), e1 = exp2_fast(L1);
            float e2 = exp2_fast(L2), e3 = exp2_fast(L3);
            float S  = quad_sum((e0 + e1) + (e2 + e3));
            float t0 = e0 * p0, t1 = e1 * p1, t2 = e2 * p2, t3 = e3 * p3;
            float A  = quad_sum((t0 * t0 + t1 * t1) + (t2 * t2 + t3 * t3));
            float Ssq = S * S;
            float ko = A * rsq_fast(fmaf(EPS, Ssq, A)) * rcp_fast(Ssq + A);
            f32x4 r;
            r.x = ko * t0; r.y = ko * t1; r.z = ko * t2; r.w = ko * t3;
            __builtin_nontemporal_store(
                r, reinterpret_cast<f32x4*>(obase + n * (UU * CC * DD)));
        }
    }
}

extern "C" void kernel_launch(void* const* d_in, const int* in_sizes, int n_in,
                              void* d_out, int out_size, void* d_ws, size_t ws_size,
                              hipStream_t stream) {
    const float* inputs  = (const float*)d_in[0];
    const float* weights = (const float*)d_in[1];
    float* out = (float*)d_out;

    const long long total = (long long)BB * UU * CC * 4;  // 1,179,648 = 4608*256
    const int block = 256;
    const int grid = (int)(total / block);                // exact
    caps_route_kernel<<<grid, block, 0, stream>>>(inputs, weights, out);
}

// Round 7
// 43.325 us; speedup vs baseline: 1.7646x; 1.0349x over previous
//
#include <hip/hip_runtime.h>

// Problem constants (from reference setup_inputs)
#define BB 32     // batch
#define UU 1152   // input_units
#define NN 10     // num_units
#define CC 8      // input_channels
#define DD 16     // channels_per_unit
#define EPS 1e-8f
#define INV_LN2 1.44269504088896341f

// inputs : (B, C, U)        float32
// weights: (U, N, C, D)     float32
// out    : (B, N, U, C, D)  float32
//
// R7 = R6 with PLAIN stores (single-lever A/B vs nontemporal).
// Everything else identical:
//  - one thread per (b,u,c,sub-quad), n-loop over 10 num_units, unroll 2
//  - squash coefficient folded: k_o = A * rsqrt(A + eps*S^2) * rcp(S^2 + A)
//  - iter1 via m = e*q (t never materialized)
//  - base-2 logit domain, raw v_exp_f32
//  - __launch_bounds__(256, 8)

typedef float f32x4 __attribute__((ext_vector_type(4)));

__device__ __forceinline__ float rcp_fast(float x) { return __builtin_amdgcn_rcpf(x); }
__device__ __forceinline__ float rsq_fast(float x) { return __builtin_amdgcn_rsqf(x); }

#if __has_builtin(__builtin_amdgcn_exp2f)
__device__ __forceinline__ float exp2_fast(float x) { return __builtin_amdgcn_exp2f(x); }
#else
__device__ __forceinline__ float exp2_fast(float x) { return __expf(x * 0.6931471805599453f); }
#endif

// sum across the 4 lanes of a quad — pure-VALU DPP butterfly
__device__ __forceinline__ float quad_sum(float x) {
    float y = __int_as_float(
        __builtin_amdgcn_update_dpp(0, __float_as_int(x), 0xB1, 0xF, 0xF, true)); // [1,0,3,2]
    x += y;
    y = __int_as_float(
        __builtin_amdgcn_update_dpp(0, __float_as_int(x), 0x4E, 0xF, 0xF, true)); // [2,3,0,1]
    return x + y;
}

__global__ __launch_bounds__(256, 8) void caps_route_kernel(
    const float* __restrict__ inputs,
    const float* __restrict__ weights,
    float* __restrict__ out)
{
    int t = blockIdx.x * blockDim.x + threadIdx.x;  // 1,179,648 threads
    int sub = t & 3;          // 4-element slice of D
    int g   = t >> 2;         // (b, u, c) group
    int c   = g & 7;
    int g2  = g >> 3;
    int u   = g2 % UU;
    int b   = g2 / UU;

    float v = inputs[(b * CC + c) * UU + u];

    const float* wbase = weights + (u * NN * CC + c) * DD + sub * 4;
    float*       obase = out + ((b * NN * UU + u) * CC + c) * DD + sub * 4;

    #pragma unroll 2
    for (int n = 0; n < NN; ++n) {
        f32x4 w4 = *reinterpret_cast<const f32x4*>(wbase + n * (CC * DD));
        float p0 = w4.x * v, p1 = w4.y * v, p2 = w4.z * v, p3 = w4.w * v;
        float q0 = p0 * p0, q1 = p1 * p1, q2 = p2 * p2, q3 = p3 * p3;

        // ---- iter 0 (folded): softmax uniform; L = scale0*INV_LN2/16 * q ----
        float sq0 = quad_sum((q0 + q1) + (q2 + q3)) * (1.0f / 256.0f);
        float kk = sq0 * rcp_fast(1.0f + sq0) * rsq_fast(sq0 + EPS)
                   * (INV_LN2 / 16.0f);
        float L0 = kk * q0, L1 = kk * q1, L2 = kk * q2, L3 = kk * q3;

        // ---- iter 1 (base-2 logit update via m = e*q) ----
        {
            float e0 = exp2_fast(L0), e1 = exp2_fast(L1);
            float e2 = exp2_fast(L2), e3 = exp2_fast(L3);
            float S  = quad_sum((e0 + e1) + (e2 + e3));
            float m0 = e0 * q0, m1 = e1 * q1, m2 = e2 * q2, m3 = e3 * q3;
            float A  = quad_sum((m0 * e0 + m1 * e1) + (m2 * e2 + m3 * e3));
            float Ssq = S * S;
            float k = A * rsq_fast(fmaf(EPS, Ssq, A)) * rcp_fast(Ssq + A)
                      * INV_LN2;
            L0 = fmaf(k, m0, L0); L1 = fmaf(k, m1, L1);
            L2 = fmaf(k, m2, L2); L3 = fmaf(k, m3, L3);
        }

        // ---- iter 2 (final; logit update dead) ----
        {
            float e0 = exp2_fast(L0), e1 = exp2_fast(L1);
            float e2 = exp2_fast(L2), e3 = exp2_fast(L3);
            float S  = quad_sum((e0 + e1) + (e2 + e3));
            float t0 = e0 * p0, t1 = e1 * p1, t2 = e2 * p2, t3 = e3 * p3;
            float A  = quad_sum((t0 * t0 + t1 * t1) + (t2 * t2 + t3 * t3));
            float Ssq = S * S;
            float ko = A * rsq_fast(fmaf(EPS, Ssq, A)) * rcp_fast(Ssq + A);
            f32x4 r;
            r.x = ko * t0; r.y = ko * t1; r.z = ko * t2; r.w = ko * t3;
            *reinterpret_cast<f32x4*>(obase + n * (UU * CC * DD)) = r;
        }
    }
}

extern "C" void kernel_launch(void* const* d_in, const int* in_sizes, int n_in,
                              void* d_out, int out_size, void* d_ws, size_t ws_size,
                              hipStream_t stream) {
    const float* inputs  = (const float*)d_in[0];
    const float* weights = (const float*)d_in[1];
    float* out = (float*)d_out;

    const long long total = (long long)BB * UU * CC * 4;  // 1,179,648 = 4608*256
    const int block = 256;
    const int grid = (int)(total / block);                // exact
    caps_route_kernel<<<grid, block, 0, stream>>>(inputs, weights, out);
}